// Round 14
// baseline (134.513 us; speedup 1.0000x reference)
//
#include <hip/hip_runtime.h>
#include <math.h>

#define NA 8192
#define NE 32768
#define NT 256
#define JSPLIT 64
#define JCHUNK (NA / JSPLIT)   /* 128 j-atoms per steric tile */
#define NIB 8                  /* i-blocks: NA/(NT*4), ITILE=4 */

// ---- workspace layout (4-byte element offsets) ----
#define WS_DEG      0                      // int NA
#define WS_LOSS     (WS_DEG + NA)          // f32 4  [0]=valence [1]=bond [2]=steric
#define WS_DD       (WS_LOSS + 4)          // f32 3NA  combined push+bond delta
#define WS_ZERO_END (WS_DD + 3*NA)         // memset zeroes [0, here) = 131 KB
#define WS_PART     ((WS_ZERO_END + 3) & ~3)  // float4 JSPLIT*NA = 8 MB, 16B aligned
// R8 ran the jsplit=64 path (8.3 MB WRITE_SIZE observed) -> ws_size >= 8.6 MB proven

// ---- chemistry tables (types present: {1,6,7,8,9,15,16,17}) ----
__device__ __forceinline__ float maxval_of(int z) {
    switch (z) {
        case 1: return 1.f; case 6: return 4.f; case 7: return 3.f; case 8: return 2.f;
        case 9: return 1.f; case 15: return 5.f; case 16: return 6.f; case 17: return 1.f;
        case 35: return 1.f; case 53: return 1.f; default: return 4.f;
    }
}
__device__ __forceinline__ float vdw_of(int z) {
    switch (z) {
        case 1: return 1.2f; case 6: return 1.7f; case 7: return 1.55f; case 8: return 1.52f;
        case 9: return 1.47f; case 15: return 1.8f; case 16: return 1.8f; case 17: return 1.75f;
        case 35: return 1.85f; case 53: return 1.98f; default: return 1.6f;
    }
}
__device__ __forceinline__ float bond_of(int a, int b) {
    int lo = a < b ? a : b, hi = a < b ? b : a;
    switch (lo * 64 + hi) {
        case 6*64+6:   return 1.54f;
        case 6*64+7:   return 1.47f;
        case 6*64+8:   return 1.43f;
        case 6*64+16:  return 1.82f;
        case 6*64+9:   return 1.35f;
        case 6*64+17:  return 1.77f;
        case 1*64+6:   return 1.09f;
        case 7*64+7:   return 1.45f;
        case 7*64+8:   return 1.40f;
        case 1*64+7:   return 1.01f;
        case 8*64+8:   return 1.48f;
        case 1*64+8:   return 0.96f;
        case 16*64+16: return 2.05f;
        case 8*64+15:  return 1.63f;
        default:       return 1.5f;
    }
}
__device__ __forceinline__ float viol_of(int d, int z) {
    return fmaxf((float)d - maxval_of(z), 0.f);
}

__device__ __forceinline__ float wave_reduce_sum(float x) {
    #pragma unroll
    for (int off = 32; off > 0; off >>= 1) x += __shfl_down(x, off);
    return x;  // valid in lane 0 of each wave
}

// ---- 1. out-degree histogram (int atomics only; must precede k_edge) ----
__global__ void k_deg(const int* __restrict__ row, int* __restrict__ deg) {
    int e = blockIdx.x * NT + threadIdx.x;
    if (e < NE) atomicAdd(&deg[row[e]], 1);
}

// ---- 2. fused bond + valence push + both losses (round-10 form, kept) ----
__global__ void k_edge(const int* __restrict__ row, const int* __restrict__ col,
                       const int* __restrict__ types, const int* __restrict__ deg,
                       const float* __restrict__ pos, float* __restrict__ dD,
                       float* __restrict__ lossAcc) {
    int e = blockIdx.x * NT + threadIdx.x;
    float l1 = 0.f, l0 = 0.f;
    if (e < NE) {
        int r = row[e], c = col[e];
        float bx = pos[3*r]   - pos[3*c];
        float by = pos[3*r+1] - pos[3*c+1];
        float bz = pos[3*r+2] - pos[3*c+2];
        float cur = sqrtf(bx*bx + by*by + bz*bz);
        float tgt = bond_of(types[r], types[c]);
        float diff = cur - tgt;
        l1 = diff * diff;
        float rcur = 1.0f / (cur + 1e-8f);        // single divide
        float ratio = fminf(fmaxf(tgt * rcur, 0.98f), 1.02f);
        float s = (ratio - 1.f) * 0.005f;
        float v = viol_of(deg[r], types[r]);
        float sc = (v > 0.f) ? (v * 1e-3f * rcur) : 0.f;   // self-edge: b=0 anyway
        float rs = s + sc;
        atomicAdd(&dD[3*r],   bx * rs);
        atomicAdd(&dD[3*r+1], by * rs);
        atomicAdd(&dD[3*r+2], bz * rs);
        atomicAdd(&dD[3*c],   -bx * s);
        atomicAdd(&dD[3*c+1], -by * s);
        atomicAdd(&dD[3*c+2], -bz * s);
    }
    if (e < NA) {                              // valence loss (deg complete here)
        float v = viol_of(deg[e], types[e]);
        l0 = v * v;
    }
    float p1 = wave_reduce_sum(l1);
    float p0 = wave_reduce_sum(l0);
    if ((threadIdx.x & 63) == 0) {
        if (p1 != 0.f) atomicAdd(&lossAcc[1], p1);
        if (p0 != 0.f) atomicAdd(&lossAcc[0], p0);
    }
}

// round-9 proven pair form (fastest of all arithmetic variants tried)
__device__ __forceinline__ void steric_pair(const float4 p, const float4 q,
                                            float& cs, float& sx, float& sy, float& sz,
                                            float& ll) {
    float dx = p.x - q.x, dy = p.y - q.y, dz = p.z - q.z;
    float d2 = fmaf(dx, dx, fmaf(dy, dy, dz * dz));
    float md = p.w + q.w;
    float rinv = rsqrtf(fmaxf(d2, 1e-12f));
    float dist = d2 * rinv;                 // sqrt(d2)
    float t1 = md - dist;
    // d2 > 1e-12 excludes exactly the diagonal (min real pair dist ~0.04)
    bool ok = (t1 > 0.f) && (d2 > 1e-12f);
    float t1c = ok ? t1 : 0.f;
    ll = fmaf(t1c, t1c, ll);
    float co = t1c * rinv;
    cs += co;
    sx = fmaf(co, q.x, sx);
    sy = fmaf(co, q.y, sy);
    sz = fmaf(co, q.z, sz);
}

// ---- 3. steric all-pairs -> non-atomic partial[y][a].
// ITILE=4 x JCHUNK=128 at the SAME 512 blocks: identical pairs/thread and
// occupancy as the 51.5us round-9 config, but 4 independent latency chains
// per thread (vs 2), half the LDS q-reads per pair, half the loop iterations.
__global__ void __launch_bounds__(NT)
k_steric(const float* __restrict__ pos, const float* __restrict__ dD,
         const int* __restrict__ types, float4* __restrict__ partial,
         float* __restrict__ lossAcc) {
    __shared__ float4 sm[JCHUNK];
    const int t = threadIdx.x;
    const int b = blockIdx.x;
    const int yb = b >> 3;                 // [0,64) j-slice
    const int ib = b & 7;                  // [0,8) i-block of 1024 atoms
    if (t < JCHUNK) {
        int j = yb * JCHUNK + t;
        sm[t] = make_float4(pos[3*j]   + dD[3*j],
                            pos[3*j+1] + dD[3*j+1],
                            pos[3*j+2] + dD[3*j+2],
                            vdw_of(types[j]) * 0.8f);
    }
    const int i0 = ib * 1024 + t;
    const int i1 = i0 + 256;
    const int i2 = i0 + 512;
    const int i3 = i0 + 768;
    float4 p0 = make_float4(pos[3*i0] + dD[3*i0], pos[3*i0+1] + dD[3*i0+1],
                            pos[3*i0+2] + dD[3*i0+2], vdw_of(types[i0]) * 0.8f);
    float4 p1 = make_float4(pos[3*i1] + dD[3*i1], pos[3*i1+1] + dD[3*i1+1],
                            pos[3*i1+2] + dD[3*i1+2], vdw_of(types[i1]) * 0.8f);
    float4 p2 = make_float4(pos[3*i2] + dD[3*i2], pos[3*i2+1] + dD[3*i2+1],
                            pos[3*i2+2] + dD[3*i2+2], vdw_of(types[i2]) * 0.8f);
    float4 p3 = make_float4(pos[3*i3] + dD[3*i3], pos[3*i3+1] + dD[3*i3+1],
                            pos[3*i3+2] + dD[3*i3+2], vdw_of(types[i3]) * 0.8f);
    __syncthreads();
    float cs0 = 0.f, sx0 = 0.f, sy0 = 0.f, sz0 = 0.f;
    float cs1 = 0.f, sx1 = 0.f, sy1 = 0.f, sz1 = 0.f;
    float cs2 = 0.f, sx2 = 0.f, sy2 = 0.f, sz2 = 0.f;
    float cs3 = 0.f, sx3 = 0.f, sy3 = 0.f, sz3 = 0.f;
    float ll = 0.f;
    #pragma unroll 4
    for (int jj = 0; jj < JCHUNK; jj++) {
        float4 q = sm[jj];
        steric_pair(p0, q, cs0, sx0, sy0, sz0, ll);
        steric_pair(p1, q, cs1, sx1, sy1, sz1, ll);
        steric_pair(p2, q, cs2, sx2, sy2, sz2, ll);
        steric_pair(p3, q, cs3, sx3, sy3, sz3, ll);
    }
    partial[yb * NA + i0] = make_float4(cs0, sx0, sy0, sz0);
    partial[yb * NA + i1] = make_float4(cs1, sx1, sy1, sz1);
    partial[yb * NA + i2] = make_float4(cs2, sx2, sy2, sz2);
    partial[yb * NA + i3] = make_float4(cs3, sx3, sy3, sz3);
    float part = wave_reduce_sum(ll);
    if ((t & 63) == 0 && part != 0.f) atomicAdd(&lossAcc[2], part);
}

// ---- 4. reduce 64 slices/atom (coalesced) + final output + loss scalar ----
__global__ void k_reduce(const float* __restrict__ pos, const float* __restrict__ dD,
                         const float4* __restrict__ partial,
                         const float* __restrict__ lossAcc, float* __restrict__ out) {
    int a = blockIdx.x * NT + threadIdx.x;   // 32 blocks x 256 = NA
    float cs = 0.f, sx = 0.f, sy = 0.f, sz = 0.f;
    #pragma unroll 8
    for (int y = 0; y < JSPLIT; y++) {
        float4 u = partial[y * NA + a];      // coalesced: consecutive a per lane
        cs += u.x; sx += u.y; sy += u.z; sz += u.w;
    }
    float px = pos[3*a]   + dD[3*a];
    float py = pos[3*a+1] + dD[3*a+1];
    float pz = pos[3*a+2] + dD[3*a+2];
    float c = 1.f + cs * 0.0025f;
    out[3*a]   = px * c - sx * 0.0025f;
    out[3*a+1] = py * c - sy * 0.0025f;
    out[3*a+2] = pz * c - sz * 0.0025f;
    if (a == 0) {
        float loss = lossAcc[0] + lossAcc[1] * (1.f / NE) + lossAcc[2] * 0.5f;
        out[3*NA] = loss * 0.1f;
    }
}

extern "C" void kernel_launch(void* const* d_in, const int* in_sizes, int n_in,
                              void* d_out, int out_size, void* d_ws, size_t ws_size,
                              hipStream_t stream) {
    (void)in_sizes; (void)n_in; (void)out_size; (void)ws_size;
    const float* pos   = (const float*)d_in[0];
    const int*   eidx  = (const int*)d_in[1];
    const int*   types = (const int*)d_in[2];
    const int* row = eidx;
    const int* col = eidx + NE;

    int*   ws_i = (int*)d_ws;
    float* ws_f = (float*)d_ws;
    int*    deg     = ws_i + WS_DEG;
    float*  lossAcc = ws_f + WS_LOSS;
    float*  dD      = ws_f + WS_DD;
    float4* partial = (float4*)(ws_f + WS_PART);
    float*  out     = (float*)d_out;

    hipMemsetAsync(d_ws, 0, (size_t)WS_ZERO_END * 4, stream);  // deg, loss, dD
    k_deg   <<<NE/NT, NT, 0, stream>>>(row, deg);
    k_edge  <<<NE/NT, NT, 0, stream>>>(row, col, types, deg, pos, dD, lossAcc);
    k_steric<<<JSPLIT*NIB, NT, 0, stream>>>(pos, dD, types, partial, lossAcc);
    k_reduce<<<NA/NT, NT, 0, stream>>>(pos, dD, partial, lossAcc, out);
}